// Round 9
// baseline (84.211 us; speedup 1.0000x reference)
//
#include <hip/hip_runtime.h>
#include <hip/hip_bf16.h>

typedef __bf16 bf16x8 __attribute__((ext_vector_type(8)));
typedef __bf16 bf16x4 __attribute__((ext_vector_type(4)));
typedef float f32x4 __attribute__((ext_vector_type(4)));

#define WORLD 8
#define M_DIM 8192
#define N_DIM 2048
#define KL 256
#define K_TOT 2048

#define BM 256
#define BN 256
#define BK 32
#define NT (K_TOT / BK)   // 64 K-tiles of 32

#define AS1 __attribute__((address_space(1)))
#define AS3 __attribute__((address_space(3)))

#define BAR()    __builtin_amdgcn_s_barrier()
#define VMCNT2() asm volatile("s_waitcnt vmcnt(2)" ::: "memory")
#define VMCNT0() asm volatile("s_waitcnt vmcnt(0)" ::: "memory")
#define PRIO1()  __builtin_amdgcn_s_setprio(1)
#define PRIO0()  __builtin_amdgcn_s_setprio(0)

// ---------------------------------------------------------------------------
// Pass 1: fp32 -> bf16 conversion + rank-dim gather (unchanged).
// ---------------------------------------------------------------------------
__global__ __launch_bounds__(256) void GemmRS_convert_kernel(
    const float* __restrict__ A,
    const float* __restrict__ W,
    __bf16* __restrict__ Abf,
    __bf16* __restrict__ Wbf)
{
    const long long GA = (long long)WORLD * M_DIM * KL / 4;
    const long long GW = (long long)WORLD * N_DIM * KL / 4;
    const long long stride = (long long)gridDim.x * blockDim.x;
    for (long long g = (long long)blockIdx.x * blockDim.x + threadIdx.x;
         g < GA + GW; g += stride) {
        if (g < GA) {
            const long long e = g * 4;
            const int k = (int)(e & (KL - 1));
            const int m = (int)((e >> 8) & (M_DIM - 1));
            const int r = (int)(e >> 21);
            const float4 v = *reinterpret_cast<const float4*>(A + e);
            bf16x4 o;
            o[0] = (__bf16)v.x; o[1] = (__bf16)v.y;
            o[2] = (__bf16)v.z; o[3] = (__bf16)v.w;
            *reinterpret_cast<bf16x4*>(Abf + (size_t)m * K_TOT + r * KL + k) = o;
        } else {
            const long long e = (g - GA) * 4;
            const int k = (int)(e & (KL - 1));
            const int n = (int)((e >> 8) & (N_DIM - 1));
            const int r = (int)(e >> 19);
            const float4 v = *reinterpret_cast<const float4*>(W + e);
            bf16x4 o;
            o[0] = (__bf16)v.x; o[1] = (__bf16)v.y;
            o[2] = (__bf16)v.z; o[3] = (__bf16)v.w;
            *reinterpret_cast<bf16x4*>(Wbf + (size_t)n * K_TOT + r * KL + k) = o;
        }
    }
}

// ---------------------------------------------------------------------------
// Pass 2 (R9): 256x256 tile, 16 waves (4x4) x 64x64 out, BK=32,
// 3-buffer LDS ring (96 KiB), <=128 regs/wave -> 4 waves/SIMD.
// Two phases per K-tile:
//   PhA: 8 ds_read (A4+B4) -> BAR -> 8 MFMA (fb 0,1)
//   PhB: stage tile t+2 (2 gload_lds) -> vmcnt(2) -> BAR -> 8 MFMA (fb 2,3)
// Swizzle: LDS row = 32 elems (4x16B granules); read granule g2^((r15>>1)&3);
// staged linear-dest with inverse-swizzled global source column.
// ---------------------------------------------------------------------------

__global__ __launch_bounds__(1024, 4) void GemmRS_gemm_kernel(
    const __bf16* __restrict__ Abf,   // [M][K_TOT]
    const __bf16* __restrict__ Wbf,   // [N][K_TOT]
    float* __restrict__ C)            // [M][N]
{
    __shared__ __bf16 lds[3][2][BM * BK];   // 3 x (A,B) x 16 KiB = 96 KiB

    const int tid  = threadIdx.x;
    const int lane = tid & 63;
    const int wave = tid >> 6;      // 0..15
    const int wr   = wave >> 2;     // 0..3 (m quarter: 64 rows)
    const int wc   = wave & 3;      // 0..3 (n quarter: 64 cols)

    // T1: XCD-aware bijective swizzle (256 blocks, 256%8==0)
    const int bid = blockIdx.x;
    const int swz = (bid & 7) * 32 + (bid >> 3);
    const int tm = swz >> 3;        // 0..31
    const int tn = swz & 7;         // 0..7
    const size_t m0 = (size_t)tm * BM;
    const size_t n0 = (size_t)tn * BN;

    const __bf16* aptr = Abf + m0 * K_TOT;
    const __bf16* bptr = Wbf + n0 * K_TOT;

    // fragment-read geometry
    const int r15 = lane & 15;
    const int g2  = lane >> 4;                    // 0..3 (k granule)
    const int gk  = (g2 ^ ((r15 >> 1) & 3)) * 8;  // swizzled granule offset

    // stage geometry: thread covers row = wave*16 + (lane>>2), granule lane&3
    const int srow = wave * 16 + (lane >> 2);               // 0..255
    const int sg   = (lane & 3) ^ ((srow >> 1) & 3);        // inverse swizzle
    const size_t soff = (size_t)srow * K_TOT + sg * 8;

    f32x4 acc[4][4];
#pragma unroll
    for (int i = 0; i < 4; ++i)
#pragma unroll
        for (int j = 0; j < 4; ++j)
            acc[i][j] = (f32x4){0.f, 0.f, 0.f, 0.f};

    bf16x8 a[4], b[4];

    auto STAGE = [&](int bufi, int t) {
        __builtin_amdgcn_global_load_lds(
            (const AS1 void*)(aptr + soff + t * BK),
            (AS3 void*)(&lds[bufi][0][0] + wave * 512), 16, 0, 0);
        __builtin_amdgcn_global_load_lds(
            (const AS1 void*)(bptr + soff + t * BK),
            (AS3 void*)(&lds[bufi][1][0] + wave * 512), 16, 0, 0);
    };

    auto READ = [&](int bufi) {
        const __bf16* LA = &lds[bufi][0][0];
        const __bf16* LB = &lds[bufi][1][0];
#pragma unroll
        for (int f = 0; f < 4; ++f)
            a[f] = *reinterpret_cast<const bf16x8*>(
                LA + (wr * 64 + f * 16 + r15) * BK + gk);
#pragma unroll
        for (int f = 0; f < 4; ++f)
            b[f] = *reinterpret_cast<const bf16x8*>(
                LB + (wc * 64 + f * 16 + r15) * BK + gk);
    };

    // ---- prologue: stage tiles 0,1 into bufs 0,1 ----
    STAGE(0, 0);
    STAGE(1, 1);
    VMCNT2();     // tile0 landed; tile1 flying
    BAR();

    int c0 = 0, c1 = 1, c2 = 2;
    for (int t = 0; t < NT; ++t) {
        // PhA: reads + first MFMA half
        READ(c0);
        BAR();
        PRIO1();
#pragma unroll
        for (int f = 0; f < 4; ++f)
#pragma unroll
            for (int j = 0; j < 2; ++j)
                acc[f][j] = __builtin_amdgcn_mfma_f32_16x16x32_bf16(
                    a[f], b[j], acc[f][j], 0, 0, 0);
        PRIO0();

        // PhB: stage t+2 into the ring slot freed at t-1, second MFMA half
        if (t + 2 < NT) {
            STAGE(c2, t + 2);
            VMCNT2();   // ensure tile t+1 landed; t+2 flying
        } else {
            VMCNT0();   // drain the final stage(s)
        }
        BAR();
        PRIO1();
#pragma unroll
        for (int f = 0; f < 4; ++f)
#pragma unroll
            for (int j = 2; j < 4; ++j)
                acc[f][j] = __builtin_amdgcn_mfma_f32_16x16x32_bf16(
                    a[f], b[j], acc[f][j], 0, 0, 0);
        PRIO0();

        const int tmp = c0; c0 = c1; c1 = c2; c2 = tmp;
    }

    // ---- epilogue: direct stores (C/D: col=lane&15, row=(lane>>4)*4+q) ----
#pragma unroll
    for (int fa = 0; fa < 4; ++fa)
#pragma unroll
        for (int fb = 0; fb < 4; ++fb)
#pragma unroll
            for (int q = 0; q < 4; ++q)
                C[(m0 + wr * 64 + fa * 16 + g2 * 4 + q) * (size_t)N_DIM
                  + n0 + wc * 64 + fb * 16 + r15] = acc[fa][fb][q];
}

extern "C" void kernel_launch(void* const* d_in, const int* in_sizes, int n_in,
                              void* d_out, int out_size, void* d_ws, size_t ws_size,
                              hipStream_t stream) {
    (void)in_sizes; (void)n_in; (void)out_size; (void)ws_size;
    const float* A = (const float*)d_in[0];   // [8][8192][256] fp32
    const float* W = (const float*)d_in[1];   // [8][2048][256] fp32
    float* C = (float*)d_out;                 // [8192][2048] fp32

    __bf16* Abf = (__bf16*)d_ws;                                      // 32 MiB
    __bf16* Wbf = (__bf16*)((char*)d_ws + (size_t)M_DIM * K_TOT * 2); // + 8 MiB

    GemmRS_convert_kernel<<<2048, 256, 0, stream>>>(A, W, Abf, Wbf);
    GemmRS_gemm_kernel<<<(M_DIM / BM) * (N_DIM / BN), 1024, 0, stream>>>(Abf, Wbf, C);
}